// Round 1
// baseline (535.035 us; speedup 1.0000x reference)
//
#include <hip/hip_runtime.h>
#include <math.h>

// Problem constants (from reference): V=3, B=2, C=64, NS=32, H=128, W=128
constexpr int NV = 3;
constexpr int NB = 2;
constexpr int NC = 64;
constexpr int NSC = 32;
constexpr int NH = 128;
constexpr int NW = 128;

// ---------------------------------------------------------------------------
// 4x4 inverse (adjugate, double precision) — mirrors jnp.linalg.inv fidelity
// ---------------------------------------------------------------------------
__device__ void inv4x4(const double* m, double* out) {
    double inv[16];
    inv[0]  =  m[5]*m[10]*m[15] - m[5]*m[11]*m[14] - m[9]*m[6]*m[15] + m[9]*m[7]*m[14] + m[13]*m[6]*m[11] - m[13]*m[7]*m[10];
    inv[4]  = -m[4]*m[10]*m[15] + m[4]*m[11]*m[14] + m[8]*m[6]*m[15] - m[8]*m[7]*m[14] - m[12]*m[6]*m[11] + m[12]*m[7]*m[10];
    inv[8]  =  m[4]*m[9]*m[15]  - m[4]*m[11]*m[13] - m[8]*m[5]*m[15] + m[8]*m[7]*m[13] + m[12]*m[5]*m[11] - m[12]*m[7]*m[9];
    inv[12] = -m[4]*m[9]*m[14]  + m[4]*m[10]*m[13] + m[8]*m[5]*m[14] - m[8]*m[6]*m[13] - m[12]*m[5]*m[10] + m[12]*m[6]*m[9];
    inv[1]  = -m[1]*m[10]*m[15] + m[1]*m[11]*m[14] + m[9]*m[2]*m[15] - m[9]*m[3]*m[14] - m[13]*m[2]*m[11] + m[13]*m[3]*m[10];
    inv[5]  =  m[0]*m[10]*m[15] - m[0]*m[11]*m[14] - m[8]*m[2]*m[15] + m[8]*m[3]*m[14] + m[12]*m[2]*m[11] - m[12]*m[3]*m[10];
    inv[9]  = -m[0]*m[9]*m[15]  + m[0]*m[11]*m[13] + m[8]*m[1]*m[15] - m[8]*m[3]*m[13] - m[12]*m[1]*m[11] + m[12]*m[3]*m[9];
    inv[13] =  m[0]*m[9]*m[14]  - m[0]*m[10]*m[13] - m[8]*m[1]*m[14] + m[8]*m[2]*m[13] + m[12]*m[1]*m[10] - m[12]*m[2]*m[9];
    inv[2]  =  m[1]*m[6]*m[15]  - m[1]*m[7]*m[14]  - m[5]*m[2]*m[15] + m[5]*m[3]*m[14] + m[13]*m[2]*m[7]  - m[13]*m[3]*m[6];
    inv[6]  = -m[0]*m[6]*m[15]  + m[0]*m[7]*m[14]  + m[4]*m[2]*m[15] - m[4]*m[3]*m[14] - m[12]*m[2]*m[7]  + m[12]*m[3]*m[6];
    inv[10] =  m[0]*m[5]*m[15]  - m[0]*m[7]*m[13]  - m[4]*m[1]*m[15] + m[4]*m[3]*m[13] + m[12]*m[1]*m[7]  - m[12]*m[3]*m[5];
    inv[14] = -m[0]*m[5]*m[14]  + m[0]*m[6]*m[13]  + m[4]*m[1]*m[14] - m[4]*m[2]*m[13] - m[12]*m[1]*m[6]  + m[12]*m[2]*m[5];
    inv[3]  = -m[1]*m[6]*m[11]  + m[1]*m[7]*m[10]  + m[5]*m[2]*m[11] - m[5]*m[3]*m[10] - m[9]*m[2]*m[7]   + m[9]*m[3]*m[6];
    inv[7]  =  m[0]*m[6]*m[11]  - m[0]*m[7]*m[10]  - m[4]*m[2]*m[11] + m[4]*m[3]*m[10] + m[8]*m[2]*m[7]   - m[8]*m[3]*m[6];
    inv[11] = -m[0]*m[5]*m[11]  + m[0]*m[7]*m[9]   + m[4]*m[1]*m[11] - m[4]*m[3]*m[9]  - m[8]*m[1]*m[7]   + m[8]*m[3]*m[5];
    inv[15] =  m[0]*m[5]*m[10]  - m[0]*m[6]*m[9]   - m[4]*m[1]*m[10] + m[4]*m[2]*m[9]  + m[8]*m[1]*m[6]   - m[8]*m[2]*m[5];
    double det = m[0]*inv[0] + m[1]*inv[4] + m[2]*inv[8] + m[3]*inv[12];
    det = 1.0 / det;
    for (int i = 0; i < 16; ++i) out[i] = inv[i] * det;
}

__device__ void mat4mul(const double* a, const double* b, double* o) {
    for (int i = 0; i < 4; ++i)
        for (int j = 0; j < 4; ++j) {
            double s = 0.0;
            for (int k = 0; k < 4; ++k) s += a[i*4+k] * b[k*4+j];
            o[i*4+j] = s;
        }
}

// ---------------------------------------------------------------------------
// Setup: per (src view, batch) compute rot(3x3)+trans(3) of the homography
// proj = src_P @ src_w2c @ inv(ref_P @ ref_w2c)
// rt layout: (2, B, 12) = rot row-major [0..8], trans [9..11]
// ---------------------------------------------------------------------------
__global__ void setup_kernel(const float* __restrict__ intr,
                             const float* __restrict__ c2w,
                             float* __restrict__ rt) {
    int t = threadIdx.x;
    if (t >= 2 * NB) return;
    int vi = t >> 1;         // 0 -> view 1, 1 -> view 2
    int b  = t & 1;
    int v  = vi + 1;

    double src_c2w[16], ref_c2w[16];
    for (int i = 0; i < 16; ++i) {
        src_c2w[i] = (double)c2w[(v * NB + b) * 16 + i];
        ref_c2w[i] = (double)c2w[(0 * NB + b) * 16 + i];
    }
    double src_w2c[16], ref_w2c[16];
    inv4x4(src_c2w, src_w2c);
    inv4x4(ref_c2w, ref_w2c);

    double srcP[16], refP[16];
    for (int i = 0; i < 16; ++i) { srcP[i] = src_w2c[i]; refP[i] = ref_w2c[i]; }
    for (int r = 0; r < 3; ++r)
        for (int c = 0; c < 3; ++c) {
            srcP[r*4+c] = (double)intr[(v * NB + b) * 9 + r*3 + c];
            refP[r*4+c] = (double)intr[(0 * NB + b) * 9 + r*3 + c];
        }

    double M1[16], M2[16], M2inv[16], proj[16];
    mat4mul(srcP, src_w2c, M1);
    mat4mul(refP, ref_w2c, M2);
    inv4x4(M2, M2inv);
    double tmp[16];
    mat4mul(M1, M2inv, tmp);
    for (int i = 0; i < 16; ++i) proj[i] = tmp[i];

    float* o = rt + (vi * NB + b) * 12;
    o[0] = (float)proj[0];  o[1] = (float)proj[1];  o[2]  = (float)proj[2];
    o[3] = (float)proj[4];  o[4] = (float)proj[5];  o[5]  = (float)proj[6];
    o[6] = (float)proj[8];  o[7] = (float)proj[9];  o[8]  = (float)proj[10];
    o[9] = (float)proj[3];  o[10] = (float)proj[7]; o[11] = (float)proj[11];
}

// ---------------------------------------------------------------------------
// Transpose features (V*B, C, H, W) -> (V*B, H, W, C) so the 64 channels at a
// (y,x) tap are contiguous (one coalesced 256B wave load, lane = channel).
// One block per (vb, y) row. LDS tile padded +1 to kill bank conflicts.
// ---------------------------------------------------------------------------
__global__ __launch_bounds__(256) void transpose_kernel(const float* __restrict__ in,
                                                        float* __restrict__ out) {
    __shared__ float tile[NC][NW + 1];
    const int y  = blockIdx.x;
    const int vb = blockIdx.y;

    for (int i = threadIdx.x; i < NC * NW; i += 256) {
        int c = i >> 7;          // /128
        int x = i & (NW - 1);
        tile[c][x] = in[((size_t)(vb * NC + c) * NH + y) * NW + x];
    }
    __syncthreads();
    float* dst = out + ((size_t)vb * NH + y) * NW * NC;
    for (int i = threadIdx.x; i < NC * NW; i += 256) {
        int x = i >> 6;          // /64
        int c = i & (NC - 1);
        dst[x * NC + c] = tile[c][x];
    }
}

// ---------------------------------------------------------------------------
// Main cost kernel. Grid: (y=H, ns=NS, b=B), block 256 = 4 waves.
// Wave w handles x in [w*32, w*32+32). lane = channel.
// Per pixel: load ref channel, for each of 2 views compute warp coords
// (lane-uniform), 4 coalesced tap loads, bilinear, residual update, butterfly
// reduce sum of squares over 64 lanes, sqrt, accumulate.
// One atomicAdd per wave into cost[b, ns].
// ---------------------------------------------------------------------------
__global__ __launch_bounds__(256) void cost_kernel(
    const float* __restrict__ ft,     // (V, B, H, W, C) transposed features
    const float* __restrict__ depth,  // (B, H, W)
    const float* __restrict__ scale,  // (B, NS)
    const float* __restrict__ rt,     // (2, B, 12)
    float* __restrict__ cost)         // (B, NS) -- pre-zeroed
{
    const int y    = blockIdx.x;
    const int ns   = blockIdx.y;
    const int b    = blockIdx.z;
    const int lane = threadIdx.x & 63;
    const int wave = threadIdx.x >> 6;

    const float s = scale[b * NSC + ns];
    const float* f0 = ft + (((size_t)(0 * NB + b) * NH + y) * NW) * NC;
    const float* fv1 = ft + ((size_t)(1 * NB + b) * NH) * NW * NC;
    const float* fv2 = ft + ((size_t)(2 * NB + b) * NH) * NW * NC;
    const float* dr = depth + (b * NH + y) * NW;

    float R[2][12];
#pragma unroll
    for (int vi = 0; vi < 2; ++vi)
#pragma unroll
        for (int k = 0; k < 12; ++k) R[vi][k] = rt[(vi * NB + b) * 12 + k];

    const float fy = (float)y;
    float cost_acc = 0.f;

    for (int xi = 0; xi < NW / 4; ++xi) {
        const int x = wave * (NW / 4) + xi;
        const float fx = (float)x;
        const float d = dr[x] * s;
        float r = f0[x * NC + lane];

#pragma unroll
        for (int vi = 0; vi < 2; ++vi) {
            const float* fv = vi ? fv2 : fv1;
            float px = (R[vi][0] * fx + R[vi][1] * fy + R[vi][2]) * d + R[vi][9];
            float py = (R[vi][3] * fx + R[vi][4] * fy + R[vi][5]) * d + R[vi][10];
            float pz = (R[vi][6] * fx + R[vi][7] * fy + R[vi][8]) * d + R[vi][11];
            // replicate reference expression sequence exactly
            float sx = px / pz;
            float sy = py / pz;
            float gx = sx / ((NW - 1) * 0.5f) - 1.f;
            float gy = sy / ((NH - 1) * 0.5f) - 1.f;
            float ix = ((gx + 1.f) * NW - 1.f) * 0.5f;
            float iy = ((gy + 1.f) * NH - 1.f) * 0.5f;

            float x0f = floorf(ix), y0f = floorf(iy);
            float x1f = x0f + 1.f,  y1f = y0f + 1.f;
            float wx1 = ix - x0f, wx0 = 1.f - wx1;
            float wy1 = iy - y0f, wy0 = 1.f - wy1;

            bool vx0 = (x0f >= 0.f) && (x0f <= (float)(NW - 1));
            bool vx1 = (x1f >= 0.f) && (x1f <= (float)(NW - 1));
            bool vy0 = (y0f >= 0.f) && (y0f <= (float)(NH - 1));
            bool vy1 = (y1f >= 0.f) && (y1f <= (float)(NH - 1));

            int xi0 = (int)fminf(fmaxf(x0f, 0.f), (float)(NW - 1));
            int xi1 = (int)fminf(fmaxf(x1f, 0.f), (float)(NW - 1));
            int yi0 = (int)fminf(fmaxf(y0f, 0.f), (float)(NH - 1));
            int yi1 = (int)fminf(fmaxf(y1f, 0.f), (float)(NH - 1));

            float w00 = (vx0 && vy0) ? wx0 * wy0 : 0.f;
            float w01 = (vx1 && vy0) ? wx1 * wy0 : 0.f;
            float w10 = (vx0 && vy1) ? wx0 * wy1 : 0.f;
            float w11 = (vx1 && vy1) ? wx1 * wy1 : 0.f;

            float acc = fv[((size_t)yi0 * NW + xi0) * NC + lane] * w00
                      + fv[((size_t)yi0 * NW + xi1) * NC + lane] * w01
                      + fv[((size_t)yi1 * NW + xi0) * NC + lane] * w10
                      + fv[((size_t)yi1 * NW + xi1) * NC + lane] * w11;
            r -= acc;

            float sq = r * r;
#pragma unroll
            for (int m = 1; m < 64; m <<= 1) sq += __shfl_xor(sq, m, 64);
            cost_acc += sqrtf(sq);
        }
    }

    cost_acc *= 0.5f / (float)(NH * NW);   // /(V-1) and mean over H*W
    if (lane == 0) atomicAdd(&cost[b * NSC + ns], cost_acc);
}

// ---------------------------------------------------------------------------
// Finalize: softmax over NS per batch, weighted sum with scale_hypo -> out[B]
// 64 threads: lane group of 32 per batch.
// ---------------------------------------------------------------------------
__global__ void finalize_kernel(const float* __restrict__ cost,
                                const float* __restrict__ scale,
                                float* __restrict__ out) {
    int tid = threadIdx.x;
    if (tid >= NB * NSC) return;
    int b = tid >> 5;
    int ns = tid & 31;
    float c = cost[b * NSC + ns];
    float sv = scale[b * NSC + ns];

    float m = c;
#pragma unroll
    for (int mk = 1; mk < 32; mk <<= 1) m = fmaxf(m, __shfl_xor(m, mk, 64));
    float e = __expf(c - m);
    float sum = e;
#pragma unroll
    for (int mk = 1; mk < 32; mk <<= 1) sum += __shfl_xor(sum, mk, 64);
    float val = (e / sum) * sv;
#pragma unroll
    for (int mk = 1; mk < 32; mk <<= 1) val += __shfl_xor(val, mk, 64);
    if (ns == 0) out[b] = val;
}

// ---------------------------------------------------------------------------
extern "C" void kernel_launch(void* const* d_in, const int* in_sizes, int n_in,
                              void* d_out, int out_size, void* d_ws, size_t ws_size,
                              hipStream_t stream) {
    const float* features   = (const float*)d_in[0];  // (V,B,C,H,W)
    const float* intrinsics = (const float*)d_in[1];  // (V,B,3,3)
    const float* cam2world  = (const float*)d_in[2];  // (V,B,4,4)
    const float* scale_hypo = (const float*)d_in[3];  // (B,NS)
    const float* depth_init = (const float*)d_in[4];  // (B,H,W)
    float* out = (float*)d_out;                       // (B,)

    // workspace layout
    float* ft   = (float*)d_ws;                               // V*B*H*W*C floats
    float* rt   = ft + (size_t)NV * NB * NH * NW * NC;        // 2*B*12 floats
    float* cost = rt + 2 * NB * 12;                           // B*NS floats

    hipMemsetAsync(cost, 0, NB * NSC * sizeof(float), stream);

    setup_kernel<<<1, 64, 0, stream>>>(intrinsics, cam2world, rt);

    dim3 tgrid(NH, NV * NB);
    transpose_kernel<<<tgrid, 256, 0, stream>>>(features, ft);

    dim3 cgrid(NH, NSC, NB);
    cost_kernel<<<cgrid, 256, 0, stream>>>(ft, depth_init, scale_hypo, rt, cost);

    finalize_kernel<<<1, 64, 0, stream>>>(cost, scale_hypo, out);
}

// Round 2
// 369.514 us; speedup vs baseline: 1.4479x; 1.4479x over previous
//
#include <hip/hip_runtime.h>
#include <math.h>

// Problem constants (from reference): V=3, B=2, C=64, NS=32, H=128, W=128
constexpr int NV = 3;
constexpr int NB = 2;
constexpr int NC = 64;
constexpr int NSC = 32;
constexpr int NH = 128;
constexpr int NW = 128;

// ---------------------------------------------------------------------------
// 4x4 inverse (adjugate, double precision) — mirrors jnp.linalg.inv fidelity
// ---------------------------------------------------------------------------
__device__ void inv4x4(const double* m, double* out) {
    double inv[16];
    inv[0]  =  m[5]*m[10]*m[15] - m[5]*m[11]*m[14] - m[9]*m[6]*m[15] + m[9]*m[7]*m[14] + m[13]*m[6]*m[11] - m[13]*m[7]*m[10];
    inv[4]  = -m[4]*m[10]*m[15] + m[4]*m[11]*m[14] + m[8]*m[6]*m[15] - m[8]*m[7]*m[14] - m[12]*m[6]*m[11] + m[12]*m[7]*m[10];
    inv[8]  =  m[4]*m[9]*m[15]  - m[4]*m[11]*m[13] - m[8]*m[5]*m[15] + m[8]*m[7]*m[13] + m[12]*m[5]*m[11] - m[12]*m[7]*m[9];
    inv[12] = -m[4]*m[9]*m[14]  + m[4]*m[10]*m[13] + m[8]*m[5]*m[14] - m[8]*m[6]*m[13] - m[12]*m[5]*m[10] + m[12]*m[6]*m[9];
    inv[1]  = -m[1]*m[10]*m[15] + m[1]*m[11]*m[14] + m[9]*m[2]*m[15] - m[9]*m[3]*m[14] - m[13]*m[2]*m[11] + m[13]*m[3]*m[10];
    inv[5]  =  m[0]*m[10]*m[15] - m[0]*m[11]*m[14] - m[8]*m[2]*m[15] + m[8]*m[3]*m[14] + m[12]*m[2]*m[11] - m[12]*m[3]*m[10];
    inv[9]  = -m[0]*m[9]*m[15]  + m[0]*m[11]*m[13] + m[8]*m[1]*m[15] - m[8]*m[3]*m[13] - m[12]*m[1]*m[11] + m[12]*m[3]*m[9];
    inv[13] =  m[0]*m[9]*m[14]  - m[0]*m[10]*m[13] - m[8]*m[1]*m[14] + m[8]*m[2]*m[13] + m[12]*m[1]*m[10] - m[12]*m[2]*m[9];
    inv[2]  =  m[1]*m[6]*m[15]  - m[1]*m[7]*m[14]  - m[5]*m[2]*m[15] + m[5]*m[3]*m[14] + m[13]*m[2]*m[7]  - m[13]*m[3]*m[6];
    inv[6]  = -m[0]*m[6]*m[15]  + m[0]*m[7]*m[14]  + m[4]*m[2]*m[15] - m[4]*m[3]*m[14] - m[12]*m[2]*m[7]  + m[12]*m[3]*m[6];
    inv[10] =  m[0]*m[5]*m[15]  - m[0]*m[7]*m[13]  - m[4]*m[1]*m[15] + m[4]*m[3]*m[13] + m[12]*m[1]*m[7]  - m[12]*m[3]*m[5];
    inv[14] = -m[0]*m[5]*m[14]  + m[0]*m[6]*m[13]  + m[4]*m[1]*m[14] - m[4]*m[2]*m[13] - m[12]*m[1]*m[6]  + m[12]*m[2]*m[5];
    inv[3]  = -m[1]*m[6]*m[11]  + m[1]*m[7]*m[10]  + m[5]*m[2]*m[11] - m[5]*m[3]*m[10] - m[9]*m[2]*m[7]   + m[9]*m[3]*m[6];
    inv[7]  =  m[0]*m[6]*m[11]  - m[0]*m[7]*m[10]  - m[4]*m[2]*m[11] + m[4]*m[3]*m[10] + m[8]*m[2]*m[7]   - m[8]*m[3]*m[6];
    inv[11] = -m[0]*m[5]*m[11]  + m[0]*m[7]*m[9]   + m[4]*m[1]*m[11] - m[4]*m[3]*m[9]  - m[8]*m[1]*m[7]   + m[8]*m[3]*m[5];
    inv[15] =  m[0]*m[5]*m[10]  - m[0]*m[6]*m[9]   - m[4]*m[1]*m[10] + m[4]*m[2]*m[9]  + m[8]*m[1]*m[6]   - m[8]*m[2]*m[5];
    double det = m[0]*inv[0] + m[1]*inv[4] + m[2]*inv[8] + m[3]*inv[12];
    det = 1.0 / det;
    for (int i = 0; i < 16; ++i) out[i] = inv[i] * det;
}

__device__ void mat4mul(const double* a, const double* b, double* o) {
    for (int i = 0; i < 4; ++i)
        for (int j = 0; j < 4; ++j) {
            double s = 0.0;
            for (int k = 0; k < 4; ++k) s += a[i*4+k] * b[k*4+j];
            o[i*4+j] = s;
        }
}

// ---------------------------------------------------------------------------
// Setup: per (src view, batch) compute rot(3x3)+trans(3) of the homography
// proj = src_P @ src_w2c @ inv(ref_P @ ref_w2c)
// rt layout: (2, B, 12) = rot row-major [0..8], trans [9..11]
// ---------------------------------------------------------------------------
__global__ void setup_kernel(const float* __restrict__ intr,
                             const float* __restrict__ c2w,
                             float* __restrict__ rt) {
    int t = threadIdx.x;
    if (t >= 2 * NB) return;
    int vi = t >> 1;         // 0 -> view 1, 1 -> view 2
    int b  = t & 1;
    int v  = vi + 1;

    double src_c2w[16], ref_c2w[16];
    for (int i = 0; i < 16; ++i) {
        src_c2w[i] = (double)c2w[(v * NB + b) * 16 + i];
        ref_c2w[i] = (double)c2w[(0 * NB + b) * 16 + i];
    }
    double src_w2c[16], ref_w2c[16];
    inv4x4(src_c2w, src_w2c);
    inv4x4(ref_c2w, ref_w2c);

    double srcP[16], refP[16];
    for (int i = 0; i < 16; ++i) { srcP[i] = src_w2c[i]; refP[i] = ref_w2c[i]; }
    for (int r = 0; r < 3; ++r)
        for (int c = 0; c < 3; ++c) {
            srcP[r*4+c] = (double)intr[(v * NB + b) * 9 + r*3 + c];
            refP[r*4+c] = (double)intr[(0 * NB + b) * 9 + r*3 + c];
        }

    double M1[16], M2[16], M2inv[16];
    mat4mul(srcP, src_w2c, M1);
    mat4mul(refP, ref_w2c, M2);
    inv4x4(M2, M2inv);
    double proj[16];
    mat4mul(M1, M2inv, proj);

    float* o = rt + (vi * NB + b) * 12;
    o[0] = (float)proj[0];  o[1] = (float)proj[1];  o[2]  = (float)proj[2];
    o[3] = (float)proj[4];  o[4] = (float)proj[5];  o[5]  = (float)proj[6];
    o[6] = (float)proj[8];  o[7] = (float)proj[9];  o[8]  = (float)proj[10];
    o[9] = (float)proj[3];  o[10] = (float)proj[7]; o[11] = (float)proj[11];
}

// ---------------------------------------------------------------------------
// Transpose features (V*B, C, H, W) -> (V*B, H, W, C) so the 64 channels at a
// (y,x) tap are contiguous. One block per (vb, y) row. +1 pad kills conflicts.
// ---------------------------------------------------------------------------
__global__ __launch_bounds__(256) void transpose_kernel(const float* __restrict__ in,
                                                        float* __restrict__ out) {
    __shared__ float tile[NC][NW + 1];
    const int y  = blockIdx.x;
    const int vb = blockIdx.y;

    for (int i = threadIdx.x; i < NC * NW; i += 256) {
        int c = i >> 7;          // /128
        int x = i & (NW - 1);
        tile[c][x] = in[((size_t)(vb * NC + c) * NH + y) * NW + x];
    }
    __syncthreads();
    float* dst = out + ((size_t)vb * NH + y) * NW * NC;
    for (int i = threadIdx.x; i < NC * NW; i += 256) {
        int x = i >> 6;          // /64
        int c = i & (NC - 1);
        dst[x * NC + c] = tile[c][x];
    }
}

// ---------------------------------------------------------------------------
// Main cost kernel v2. Grid: (y=H, ns=NS, b=B), block 256 = 4 waves.
// Lane decomposition: 16 lanes per pixel (float4 of channels per lane),
// 4 pixels per wave. Wave w handles x in [w*32, w*32+32), 4 at a time.
// Per pixel·view: geometry computed by its 16-lane group (4x less redundant
// than lane=channel), 4 float4 tap loads, bilinear, residual, horizontal
// square + 4-shuffle group reduce, sqrt, accumulate. One atomic per wave.
// ---------------------------------------------------------------------------
__global__ __launch_bounds__(256) void cost_kernel(
    const float* __restrict__ ft,     // (V, B, H, W, C) transposed features
    const float* __restrict__ depth,  // (B, H, W)
    const float* __restrict__ scale,  // (B, NS)
    const float* __restrict__ rt,     // (2, B, 12)
    float* __restrict__ cost)         // (B, NS) -- pre-zeroed
{
    const int y    = blockIdx.x;
    const int ns   = blockIdx.y;
    const int b    = blockIdx.z;
    const int lane = threadIdx.x & 63;
    const int wave = threadIdx.x >> 6;
    const int grp  = lane >> 4;      // which of the 4 pixels in this wave
    const int gl   = lane & 15;      // float4 slot within the 64 channels

    const float s = scale[b * NSC + ns];
    const float4* f0  = (const float4*)(ft + (((size_t)(0 * NB + b) * NH + y) * NW) * NC);
    const float4* fv1 = (const float4*)(ft + ((size_t)(1 * NB + b) * NH) * NW * NC);
    const float4* fv2 = (const float4*)(ft + ((size_t)(2 * NB + b) * NH) * NW * NC);
    const float* dr = depth + (b * NH + y) * NW;

    float R[2][12];
#pragma unroll
    for (int vi = 0; vi < 2; ++vi)
#pragma unroll
        for (int k = 0; k < 12; ++k) R[vi][k] = rt[(vi * NB + b) * 12 + k];

    // ix = ((sx/((W-1)/2) - 1 + 1)*W - 1)*0.5 = sx*(W/(W-1)) - 0.5  (W even)
    const float C1X = (float)NW / (float)(NW - 1) * 0.5f * 2.0f;  // 128/127... see below
    // careful: sx/(63.5) * 128 * 0.5 = sx * (64/63.5)
    const float CX = 64.0f / 63.5f;
    const float CY = 64.0f / 63.5f;
    (void)C1X;

    const float fy = (float)y;
    float cost_acc = 0.f;

    for (int xi = 0; xi < 8; ++xi) {
        const int x = wave * 32 + xi * 4 + grp;
        const float fx = (float)x;
        const float d = dr[x] * s;
        float4 r = f0[x * (NC / 4) + gl];

#pragma unroll
        for (int vi = 0; vi < 2; ++vi) {
            const float4* fv = vi ? fv2 : fv1;
            float px = (R[vi][0] * fx + R[vi][1] * fy + R[vi][2]) * d + R[vi][9];
            float py = (R[vi][3] * fx + R[vi][4] * fy + R[vi][5]) * d + R[vi][10];
            float pz = (R[vi][6] * fx + R[vi][7] * fy + R[vi][8]) * d + R[vi][11];
            float invz = __builtin_amdgcn_rcpf(pz);
            float ix = (px * invz) * CX - 0.5f;
            float iy = (py * invz) * CY - 0.5f;

            float x0f = floorf(ix), y0f = floorf(iy);
            float wx1 = ix - x0f, wx0 = 1.f - wx1;
            float wy1 = iy - y0f, wy0 = 1.f - wy1;

            // zero-padding masks folded into the 1-D weights
            float mx0 = (x0f >= 0.f   && x0f <= 127.f) ? wx0 : 0.f;
            float mx1 = (x0f >= -1.f  && x0f <= 126.f) ? wx1 : 0.f;
            float my0 = (y0f >= 0.f   && y0f <= 127.f) ? wy0 : 0.f;
            float my1 = (y0f >= -1.f  && y0f <= 126.f) ? wy1 : 0.f;

            int xi0 = (int)fminf(fmaxf(x0f, 0.f), 127.f);
            int yi0 = (int)fminf(fmaxf(y0f, 0.f), 127.f);
            int xi1 = (int)fminf(fmaxf(x0f + 1.f, 0.f), 127.f);
            int yi1 = (int)fminf(fmaxf(y0f + 1.f, 0.f), 127.f);

            int row0 = yi0 * NW, row1 = yi1 * NW;
            float4 t00 = fv[(row0 + xi0) * (NC / 4) + gl];
            float4 t01 = fv[(row0 + xi1) * (NC / 4) + gl];
            float4 t10 = fv[(row1 + xi0) * (NC / 4) + gl];
            float4 t11 = fv[(row1 + xi1) * (NC / 4) + gl];

            float w00 = mx0 * my0, w01 = mx1 * my0;
            float w10 = mx0 * my1, w11 = mx1 * my1;

            r.x -= t00.x * w00 + t01.x * w01 + t10.x * w10 + t11.x * w11;
            r.y -= t00.y * w00 + t01.y * w01 + t10.y * w10 + t11.y * w11;
            r.z -= t00.z * w00 + t01.z * w01 + t10.z * w10 + t11.z * w11;
            r.w -= t00.w * w00 + t01.w * w01 + t10.w * w10 + t11.w * w11;

            float sq = r.x * r.x + r.y * r.y + r.z * r.z + r.w * r.w;
            sq += __shfl_xor(sq, 1, 64);
            sq += __shfl_xor(sq, 2, 64);
            sq += __shfl_xor(sq, 4, 64);
            sq += __shfl_xor(sq, 8, 64);
            cost_acc += sqrtf(sq);
        }
    }

    // lanes within a 16-lane group hold identical cost_acc; sum the 4 groups
    cost_acc += __shfl_xor(cost_acc, 16, 64);
    cost_acc += __shfl_xor(cost_acc, 32, 64);
    cost_acc *= 0.5f / (float)(NH * NW);   // /(V-1) and mean over H*W
    if (lane == 0) atomicAdd(&cost[b * NSC + ns], cost_acc);
}

// ---------------------------------------------------------------------------
// Finalize: softmax over NS per batch, weighted sum with scale_hypo -> out[B]
// ---------------------------------------------------------------------------
__global__ void finalize_kernel(const float* __restrict__ cost,
                                const float* __restrict__ scale,
                                float* __restrict__ out) {
    int tid = threadIdx.x;
    if (tid >= NB * NSC) return;
    int b = tid >> 5;
    int ns = tid & 31;
    float c = cost[b * NSC + ns];
    float sv = scale[b * NSC + ns];

    float m = c;
#pragma unroll
    for (int mk = 1; mk < 32; mk <<= 1) m = fmaxf(m, __shfl_xor(m, mk, 64));
    float e = __expf(c - m);
    float sum = e;
#pragma unroll
    for (int mk = 1; mk < 32; mk <<= 1) sum += __shfl_xor(sum, mk, 64);
    float val = (e / sum) * sv;
#pragma unroll
    for (int mk = 1; mk < 32; mk <<= 1) val += __shfl_xor(val, mk, 64);
    if (ns == 0) out[b] = val;
}

// ---------------------------------------------------------------------------
extern "C" void kernel_launch(void* const* d_in, const int* in_sizes, int n_in,
                              void* d_out, int out_size, void* d_ws, size_t ws_size,
                              hipStream_t stream) {
    const float* features   = (const float*)d_in[0];  // (V,B,C,H,W)
    const float* intrinsics = (const float*)d_in[1];  // (V,B,3,3)
    const float* cam2world  = (const float*)d_in[2];  // (V,B,4,4)
    const float* scale_hypo = (const float*)d_in[3];  // (B,NS)
    const float* depth_init = (const float*)d_in[4];  // (B,H,W)
    float* out = (float*)d_out;                       // (B,)

    // workspace layout
    float* ft   = (float*)d_ws;                               // V*B*H*W*C floats
    float* rt   = ft + (size_t)NV * NB * NH * NW * NC;        // 2*B*12 floats
    float* cost = rt + 2 * NB * 12;                           // B*NS floats

    hipMemsetAsync(cost, 0, NB * NSC * sizeof(float), stream);

    setup_kernel<<<1, 64, 0, stream>>>(intrinsics, cam2world, rt);

    dim3 tgrid(NH, NV * NB);
    transpose_kernel<<<tgrid, 256, 0, stream>>>(features, ft);

    dim3 cgrid(NH, NSC, NB);
    cost_kernel<<<cgrid, 256, 0, stream>>>(ft, depth_init, scale_hypo, rt, cost);

    finalize_kernel<<<1, 64, 0, stream>>>(cost, scale_hypo, out);
}